// Round 4
// baseline (595.689 us; speedup 1.0000x reference)
//
#include <hip/hip_runtime.h>
#include <hip/hip_cooperative_groups.h>

namespace cg = cooperative_groups;

#define T_TOK 2048
#define DM    512
#define DFF   512
#define NE    16

typedef __attribute__((ext_vector_type(8))) short bf16x8;
typedef __attribute__((ext_vector_type(4))) float f32x4;
typedef __attribute__((ext_vector_type(8))) unsigned short us8;

__device__ __forceinline__ unsigned short f2bf(float f) {
  unsigned int u = __float_as_uint(f);
  u += 0x7fffu + ((u >> 16) & 1u);   // round-to-nearest-even
  return (unsigned short)(u >> 16);
}

// async global->LDS DMA, 16 B per lane; lds base must be wave-uniform
__device__ __forceinline__ void dma16(const unsigned short* g, unsigned short* l) {
  __builtin_amdgcn_global_load_lds(
      (const __attribute__((address_space(1))) unsigned int*)g,
      (__attribute__((address_space(3))) unsigned int*)l, 16, 0, 0);
}

// XOR-swizzled LDS tile: 64 rows x 64 bf16 (128 B/row), chunk c of row r
// stored at slot c ^ (r & 7). DMA windows (1024 B) stay contiguous; readers
// get 2-way bank aliasing (free, m136).
#define LDSOFF(row, chunk) ((((row) << 7) + ((((chunk) ^ ((row) & 7))) << 4)))

#define MFMA(a,b,c) __builtin_amdgcn_mfma_f32_16x16x32_bf16((a),(b),(c),0,0,0)

struct RouterS {
  float lg[4][16];
  int bcnt[16], bbase[16];
  int sel_s[4][3], pos_s[4][3];
  float g_s[4][3];
};

// ---------------------------------------------------------------------------
// One cooperative kernel: phase0 router+convert+zero, phase1 gemm1, phase2 gemm2.
// 512 blocks x 256 threads, 2 blocks/CU (48KB LDS, launch_bounds(256,2)).
// ---------------------------------------------------------------------------
__global__ __launch_bounds__(256, 2) void moe_all(
    const float* __restrict__ x, const float* __restrict__ gw,
    const float* __restrict__ bias,
    const float* __restrict__ sgu, const float* __restrict__ sdn,
    const float* __restrict__ egu, const float* __restrict__ edn,
    int* __restrict__ counts, int* __restrict__ list, float* __restrict__ wgt,
    unsigned short* __restrict__ Hall, unsigned short* __restrict__ xb,
    unsigned short* __restrict__ sgub, unsigned short* __restrict__ sdnb,
    unsigned short* __restrict__ egub, unsigned short* __restrict__ ednb,
    float* __restrict__ out)
{
  __shared__ __align__(1024) char smem[49152];   // 48 KB, overlaid per phase
  const int bid = threadIdx.y * 0 + blockIdx.x;  // 0..511
  const int tid = threadIdx.x;
  const int w = tid >> 6, lane = tid & 63;
  cg::grid_group grid = cg::this_grid();

  // ================= phase 0: router + zero out + fp32->bf16 convert =======
  {
    RouterS& R = *(RouterS*)smem;
    if (tid < 16) R.bcnt[tid] = 0;
    const int tok = bid * 4 + w;
    const int e = lane & 15, part = lane >> 4;

    const float* xr = x + (size_t)tok * DM + part * 128;
    const float* wr = gw + (size_t)e * DM + part * 128;
    float acc = 0.f;
    #pragma unroll 8
    for (int i = 0; i < 128; i += 4) {
      float4 xv = *(const float4*)(xr + i);
      float4 wv = *(const float4*)(wr + i);
      acc += xv.x*wv.x + xv.y*wv.y + xv.z*wv.z + xv.w*wv.w;
    }
    acc += __shfl_xor(acc, 16);
    acc += __shfl_xor(acc, 32);
    if (lane < 16) R.lg[w][lane] = 1.f / (1.f + __expf(-acc));  // affinity
    __syncthreads();

    if (tid < 4) {
      float aff[16], sc[16];
      #pragma unroll
      for (int i = 0; i < 16; ++i) { aff[i] = R.lg[tid][i]; sc[i] = aff[i] + bias[i]; }
      int sel[3]; float sa[3]; float sum = 0.f;
      #pragma unroll
      for (int k = 0; k < 3; ++k) {
        float best = -1e30f; int bi = 0;
        for (int i = 0; i < 16; ++i) {
          bool used = false;
          for (int j = 0; j < k; ++j) used |= (sel[j] == i);
          if (!used && sc[i] > best) { best = sc[i]; bi = i; }
        }
        sel[k] = bi; sa[k] = aff[bi]; sum += aff[bi];
      }
      float inv = 1.f / (sum + 1e-9f);
      #pragma unroll
      for (int k = 0; k < 3; ++k) {
        int p = atomicAdd(&R.bcnt[sel[k]], 1);
        R.sel_s[tid][k] = sel[k]; R.pos_s[tid][k] = p; R.g_s[tid][k] = sa[k] * inv;
      }
    }
    __syncthreads();
    if (tid < 16) R.bbase[tid] = atomicAdd(&counts[tid], R.bcnt[tid]);
    __syncthreads();
    if (tid < 4) {
      #pragma unroll
      for (int k = 0; k < 3; ++k) {
        int E = R.sel_s[tid][k];
        int p = R.bbase[E] + R.pos_s[tid][k];
        list[E * T_TOK + p] = bid * 4 + tid;
        wgt [E * T_TOK + p] = R.g_s[tid][k];
      }
    }

    // zero out: 262144 float4 over 131072 threads -> 2 each
    const int gidx = bid * 256 + tid;
    const float4 z4 = {0.f, 0.f, 0.f, 0.f};
    ((float4*)out)[gidx] = z4;
    ((float4*)out)[gidx + 131072] = z4;

    // convert groups of 8 fp32 -> bf16:
    // x 131072 | sgu 65536 | sdn 32768 | egu 1048576 | edn 524288 = 1802240
    #pragma unroll
    for (int i = 0; i < 14; ++i) {
      const int g = gidx + i * 131072;
      if (g < 1802240) {
        const float* s; unsigned short* d; int l;
        if      (g <  131072) { s = x;   d = xb;   l = g;           }
        else if (g <  196608) { s = sgu; d = sgub; l = g -  131072; }
        else if (g <  229376) { s = sdn; d = sdnb; l = g -  196608; }
        else if (g < 1277952) { s = egu; d = egub; l = g -  229376; }
        else                  { s = edn; d = ednb; l = g - 1277952; }
        const float* p = s + (size_t)l * 8;
        float4 v0 = *(const float4*)p;
        float4 v1 = *(const float4*)(p + 4);
        us8 o;
        o[0]=f2bf(v0.x); o[1]=f2bf(v0.y); o[2]=f2bf(v0.z); o[3]=f2bf(v0.w);
        o[4]=f2bf(v1.x); o[5]=f2bf(v1.y); o[6]=f2bf(v1.z); o[7]=f2bf(v1.w);
        *(us8*)(d + (size_t)l * 8) = o;
      }
    }
  }

  __threadfence();
  grid.sync();
  __threadfence();

  // ================= phase 1: gemm1 (persistent over virtual tiles) ========
  {
    char* const sa = smem;              // SA[2][64][64] bf16, 16 KB
    char* const sg = smem + 16384;      // SG[2][64][64]
    char* const su = smem + 32768;      // SU[2][64][64]
    const int r0 = w * 16 + (lane >> 3);
    const int cch = (lane & 7) ^ (r0 & 7);
    const int wm = ((tid >> 6) & 1) * 32;
    const int wn = ((tid >> 7) & 1) * 32;
    const int lr = lane & 15, qd = lane >> 4;

    for (int v = bid; v < 8 * 32 * (NE + 1); v += 512) {
      const int bx = v & 7, mt = (v >> 3) & 31, z = v >> 8;
      const int n0 = bx * 64;
      int cnt, hb; const unsigned short* W;
      if (z == 0) { cnt = T_TOK; hb = 0; W = sgub; }
      else {
        const int e = z - 1;
        cnt = counts[e];
        if (mt * 64 >= cnt) continue;
        hb = T_TOK;
        for (int i = 0; i < e; ++i) hb += counts[i];
        W = egub + (size_t)e * (2 * DFF * DM);
      }

      const unsigned short* ga[2];
      #pragma unroll
      for (int q = 0; q < 2; ++q) {
        int ra = mt * 64 + r0 + q * 8;
        int rc = ra < cnt ? ra : cnt - 1;
        int tokr = (z == 0) ? rc : list[(z - 1) * T_TOK + rc];
        ga[q] = xb + (size_t)tokr * DM + cch * 8;
      }
      const unsigned short *gg[2], *gu[2];
      #pragma unroll
      for (int q = 0; q < 2; ++q) {
        int rb = n0 + r0 + q * 8;
        gg[q] = W + (size_t)rb * DM + cch * 8;
        gu[q] = W + (size_t)(DFF + rb) * DM + cch * 8;
      }
      unsigned short* lA[2][2]; unsigned short* lG[2][2]; unsigned short* lU[2][2];
      #pragma unroll
      for (int b = 0; b < 2; ++b)
        #pragma unroll
        for (int q = 0; q < 2; ++q) {
          const int ro = (w * 16 + q * 8) * 64;
          lA[b][q] = (unsigned short*)(sa + b * 8192) + ro;
          lG[b][q] = (unsigned short*)(sg + b * 8192) + ro;
          lU[b][q] = (unsigned short*)(su + b * 8192) + ro;
        }

      const f32x4 z4 = {0.f, 0.f, 0.f, 0.f};
      f32x4 accg[2][2], accu[2][2];
      #pragma unroll
      for (int i = 0; i < 2; ++i)
        #pragma unroll
        for (int j = 0; j < 2; ++j) { accg[i][j] = z4; accu[i][j] = z4; }

      // prologue: stage tile 0 into buf 0
      #pragma unroll
      for (int q = 0; q < 2; ++q) {
        dma16(ga[q], lA[0][q]); dma16(gg[q], lG[0][q]); dma16(gu[q], lU[0][q]);
      }

      #pragma unroll
      for (int i = 0; i < DM / 64; ++i) {
        const int b = i & 1;
        __syncthreads();                         // buf b ready (drains DMA)
        if (i + 1 < DM / 64) {
          const int k1 = (i + 1) * 64, nb = b ^ 1;
          #pragma unroll
          for (int q = 0; q < 2; ++q) {
            dma16(ga[q] + k1, lA[nb][q]);
            dma16(gg[q] + k1, lG[nb][q]);
            dma16(gu[q] + k1, lU[nb][q]);
          }
        }
        const int bo = b * 8192;
        #pragma unroll
        for (int ks = 0; ks < 2; ++ks) {
          const int ch = ks * 4 + qd;
          bf16x8 a0 = *(const bf16x8*)(sa + bo + LDSOFF(wm      + lr, ch));
          bf16x8 a1 = *(const bf16x8*)(sa + bo + LDSOFF(wm + 16 + lr, ch));
          bf16x8 g0 = *(const bf16x8*)(sg + bo + LDSOFF(wn      + lr, ch));
          bf16x8 g1 = *(const bf16x8*)(sg + bo + LDSOFF(wn + 16 + lr, ch));
          bf16x8 u0 = *(const bf16x8*)(su + bo + LDSOFF(wn      + lr, ch));
          bf16x8 u1 = *(const bf16x8*)(su + bo + LDSOFF(wn + 16 + lr, ch));
          accg[0][0] = MFMA(a0, g0, accg[0][0]);
          accg[0][1] = MFMA(a0, g1, accg[0][1]);
          accg[1][0] = MFMA(a1, g0, accg[1][0]);
          accg[1][1] = MFMA(a1, g1, accg[1][1]);
          accu[0][0] = MFMA(a0, u0, accu[0][0]);
          accu[0][1] = MFMA(a0, u1, accu[0][1]);
          accu[1][0] = MFMA(a1, u0, accu[1][0]);
          accu[1][1] = MFMA(a1, u1, accu[1][1]);
        }
      }
      __syncthreads();                           // LDS idle before next tile

      #pragma unroll
      for (int sm = 0; sm < 2; ++sm)
        #pragma unroll
        for (int sn = 0; sn < 2; ++sn) {
          const int col = n0 + wn + sn * 16 + lr;
          #pragma unroll
          for (int r = 0; r < 4; ++r) {
            const int ent = mt * 64 + wm + sm * 16 + qd * 4 + r;
            if (ent < cnt) {
              float g = accg[sm][sn][r];
              float u = accu[sm][sn][r];
              float h = (g / (1.f + __expf(-g))) * u;   // silu(g)*u
              Hall[(size_t)(hb + ent) * DFF + col] = f2bf(h);
            }
          }
        }
    }
  }

  __threadfence();
  grid.sync();
  __threadfence();

  // ================= phase 2: gemm2 (persistent over virtual tiles) ========
  {
    char* const sa = smem;              // SA[2][64][64]
    char* const sb = smem + 16384;      // SB[2][64][64]
    const int r0 = w * 16 + (lane >> 3);
    const int cch = (lane & 7) ^ (r0 & 7);
    const int wm = ((tid >> 6) & 1) * 32;
    const int wn = ((tid >> 7) & 1) * 32;
    const int lr = lane & 15, qd = lane >> 4;

    for (int v = bid; v < 8 * 32 * (NE + 1); v += 512) {
      const int bx = v & 7, mt = (v >> 3) & 31, z = v >> 8;
      const int n0 = bx * 64;
      int cnt, hb; const unsigned short* W;
      if (z == 0) { cnt = T_TOK; hb = 0; W = sdnb; }
      else {
        const int e = z - 1;
        cnt = counts[e];
        if (mt * 64 >= cnt) continue;
        hb = T_TOK;
        for (int i = 0; i < e; ++i) hb += counts[i];
        W = ednb + (size_t)e * (DM * DFF);
      }

      const unsigned short* ga[2];
      #pragma unroll
      for (int q = 0; q < 2; ++q) {
        int ra = mt * 64 + r0 + q * 8;
        int rc = ra < cnt ? ra : cnt - 1;
        ga[q] = Hall + (size_t)(hb + rc) * DFF + cch * 8;
      }
      const unsigned short* gb[2];
      #pragma unroll
      for (int q = 0; q < 2; ++q)
        gb[q] = W + (size_t)(n0 + r0 + q * 8) * DFF + cch * 8;
      unsigned short* lA[2][2]; unsigned short* lB[2][2];
      #pragma unroll
      for (int b = 0; b < 2; ++b)
        #pragma unroll
        for (int q = 0; q < 2; ++q) {
          const int ro = (w * 16 + q * 8) * 64;
          lA[b][q] = (unsigned short*)(sa + b * 8192) + ro;
          lB[b][q] = (unsigned short*)(sb + b * 8192) + ro;
        }

      const f32x4 z4 = {0.f, 0.f, 0.f, 0.f};
      f32x4 acc[2][2];
      #pragma unroll
      for (int i = 0; i < 2; ++i)
        #pragma unroll
        for (int j = 0; j < 2; ++j) acc[i][j] = z4;

      #pragma unroll
      for (int q = 0; q < 2; ++q) { dma16(ga[q], lA[0][q]); dma16(gb[q], lB[0][q]); }

      #pragma unroll
      for (int i = 0; i < DFF / 64; ++i) {
        const int b = i & 1;
        __syncthreads();
        if (i + 1 < DFF / 64) {
          const int k1 = (i + 1) * 64, nb = b ^ 1;
          #pragma unroll
          for (int q = 0; q < 2; ++q) {
            dma16(ga[q] + k1, lA[nb][q]);
            dma16(gb[q] + k1, lB[nb][q]);
          }
        }
        const int bo = b * 8192;
        #pragma unroll
        for (int ks = 0; ks < 2; ++ks) {
          const int ch = ks * 4 + qd;
          bf16x8 a0 = *(const bf16x8*)(sa + bo + LDSOFF(wm      + lr, ch));
          bf16x8 a1 = *(const bf16x8*)(sa + bo + LDSOFF(wm + 16 + lr, ch));
          bf16x8 b0 = *(const bf16x8*)(sb + bo + LDSOFF(wn      + lr, ch));
          bf16x8 b1 = *(const bf16x8*)(sb + bo + LDSOFF(wn + 16 + lr, ch));
          acc[0][0] = MFMA(a0, b0, acc[0][0]);
          acc[0][1] = MFMA(a0, b1, acc[0][1]);
          acc[1][0] = MFMA(a1, b0, acc[1][0]);
          acc[1][1] = MFMA(a1, b1, acc[1][1]);
        }
      }
      __syncthreads();                           // LDS idle before next tile

      #pragma unroll
      for (int sm = 0; sm < 2; ++sm)
        #pragma unroll
        for (int sn = 0; sn < 2; ++sn) {
          const int col = n0 + wn + sn * 16 + lr;
          #pragma unroll
          for (int r = 0; r < 4; ++r) {
            const int ent = mt * 64 + wm + sm * 16 + qd * 4 + r;
            if (ent < cnt) {
              float vv = acc[sm][sn][r];
              if (z == 0) {
                atomicAdd(out + (size_t)ent * DM + col, vv);
              } else {
                const int   tok = list[(z - 1) * T_TOK + ent];
                const float gg  = wgt [(z - 1) * T_TOK + ent];
                atomicAdd(out + (size_t)tok * DM + col, gg * vv);
              }
            }
          }
        }
    }
  }
}

// ---------------------------------------------------------------------------
extern "C" void kernel_launch(void* const* d_in, const int* in_sizes, int n_in,
                              void* d_out, int out_size, void* d_ws, size_t ws_size,
                              hipStream_t stream) {
  const float* x    = (const float*)d_in[0];
  const float* gw   = (const float*)d_in[1];
  const float* bias = (const float*)d_in[2];
  const float* sgu  = (const float*)d_in[3];
  const float* sdn  = (const float*)d_in[4];
  const float* egu  = (const float*)d_in[5];
  const float* edn  = (const float*)d_in[6];
  float* out = (float*)d_out;

  // workspace layout (bytes)
  char* ws = (char*)d_ws;
  int*            counts = (int*)(ws + 0);        // 16 ints
  int*            list   = (int*)(ws + 64);       // 16*2048 ints
  float*          wgt    = (float*)(ws + 131136); // 16*2048 floats
  unsigned short* Hall   = (unsigned short*)(ws + 262208); // 8192*512 bf16
  unsigned short* xb     = (unsigned short*)(ws + 8650816);
  unsigned short* sgub   = (unsigned short*)(ws + 10747968);
  unsigned short* sdnb   = (unsigned short*)(ws + 11796544);
  unsigned short* egub   = (unsigned short*)(ws + 12320832);
  unsigned short* ednb   = (unsigned short*)(ws + 29098048);
  const size_t need = 37486656;
  if (ws_size < need) return;

  hipMemsetAsync(counts, 0, 64, stream);

  void* args[] = {
    (void*)&x, (void*)&gw, (void*)&bias, (void*)&sgu, (void*)&sdn,
    (void*)&egu, (void*)&edn, (void*)&counts, (void*)&list, (void*)&wgt,
    (void*)&Hall, (void*)&xb, (void*)&sgub, (void*)&sdnb, (void*)&egub,
    (void*)&ednb, (void*)&out
  };
  hipLaunchCooperativeKernel((const void*)moe_all, dim3(512), dim3(256),
                             args, 0, stream);
}

// Round 5
// 163.711 us; speedup vs baseline: 3.6387x; 3.6387x over previous
//
#include <hip/hip_runtime.h>

#define T_TOK 2048
#define DM    512
#define DFF   512
#define NE    16

typedef __attribute__((ext_vector_type(8))) short bf16x8;
typedef __attribute__((ext_vector_type(4))) float f32x4;
typedef __attribute__((ext_vector_type(8))) unsigned short us8;

__device__ __forceinline__ unsigned short f2bf(float f) {
  unsigned int u = __float_as_uint(f);
  u += 0x7fffu + ((u >> 16) & 1u);   // round-to-nearest-even
  return (unsigned short)(u >> 16);
}

__device__ __forceinline__ us8 pack8(float4 v0, float4 v1) {
  us8 o;
  o[0]=f2bf(v0.x); o[1]=f2bf(v0.y); o[2]=f2bf(v0.z); o[3]=f2bf(v0.w);
  o[4]=f2bf(v1.x); o[5]=f2bf(v1.y); o[6]=f2bf(v1.z); o[7]=f2bf(v1.w);
  return o;
}

// async global->LDS DMA, 16 B per lane; lds base must be wave-uniform
__device__ __forceinline__ void dma16(const unsigned short* g, unsigned short* l) {
  __builtin_amdgcn_global_load_lds(
      (const __attribute__((address_space(1))) unsigned int*)g,
      (__attribute__((address_space(3))) unsigned int*)l, 16, 0, 0);
}

// XOR-swizzled LDS tile rows of 64 bf16 (128 B/row), chunk c of row r
// stored at slot c ^ (r & 7). DMA windows (1024 B) stay contiguous; readers
// get 2-way bank aliasing (free, m136).
#define LDSOFF(row, chunk) ((((row) << 7) + ((((chunk) ^ ((row) & 7))) << 4)))

#define MFMA(a,b,c) __builtin_amdgcn_mfma_f32_16x16x32_bf16((a),(b),(c),0,0,0)

// ---------------- prep: blocks 0..511 router, 512+ convert x|sgu|egu -------
__global__ __launch_bounds__(256) void prep_kernel(
    const float* __restrict__ x, const float* __restrict__ gw,
    const float* __restrict__ bias, int* __restrict__ counts,
    int* __restrict__ list, float* __restrict__ wgt,
    const float* __restrict__ sgu, const float* __restrict__ egu,
    unsigned short* __restrict__ xb, unsigned short* __restrict__ sgub,
    unsigned short* __restrict__ egub)
{
  const int tid = threadIdx.x;
  if (blockIdx.x >= 512) {
    // convert groups of 8 fp32->bf16: x 131072 | sgu 65536 | egu 1048576
    const int g = (blockIdx.x - 512) * 256 + tid;   // 0..1245183
    const float* s; unsigned short* d; int l;
    if      (g <  131072) { s = x;   d = xb;   l = g;          }
    else if (g <  196608) { s = sgu; d = sgub; l = g - 131072; }
    else                  { s = egu; d = egub; l = g - 196608; }
    const float* p = s + (size_t)l * 8;
    float4 v0 = *(const float4*)p;
    float4 v1 = *(const float4*)(p + 4);
    *(us8*)(d + (size_t)l * 8) = pack8(v0, v1);
    return;
  }

  // ---- router: one token per wave ----
  __shared__ float lg[4][16];
  __shared__ int bcnt[16], bbase[16];
  __shared__ int sel_s[4][3], pos_s[4][3];
  __shared__ float g_s[4][3];

  const int w = tid >> 6, lane = tid & 63;
  if (tid < 16) bcnt[tid] = 0;
  const int tok = blockIdx.x * 4 + w;
  const int e = lane & 15, part = lane >> 4;

  const float* xr = x + (size_t)tok * DM + part * 128;
  const float* wr = gw + (size_t)e * DM + part * 128;
  float acc = 0.f;
  #pragma unroll 8
  for (int i = 0; i < 128; i += 4) {
    float4 xv = *(const float4*)(xr + i);
    float4 wv = *(const float4*)(wr + i);
    acc += xv.x*wv.x + xv.y*wv.y + xv.z*wv.z + xv.w*wv.w;
  }
  acc += __shfl_xor(acc, 16);
  acc += __shfl_xor(acc, 32);
  if (lane < 16) lg[w][lane] = 1.f / (1.f + __expf(-acc));  // affinity
  __syncthreads();

  if (tid < 4) {
    float aff[16], sc[16];
    #pragma unroll
    for (int i = 0; i < 16; ++i) { aff[i] = lg[tid][i]; sc[i] = aff[i] + bias[i]; }
    int sel[3]; float sa[3]; float sum = 0.f;
    #pragma unroll
    for (int k = 0; k < 3; ++k) {
      float best = -1e30f; int bi = 0;
      for (int i = 0; i < 16; ++i) {
        bool used = false;
        for (int j = 0; j < k; ++j) used |= (sel[j] == i);
        if (!used && sc[i] > best) { best = sc[i]; bi = i; }
      }
      sel[k] = bi; sa[k] = aff[bi]; sum += aff[bi];
    }
    float inv = 1.f / (sum + 1e-9f);
    #pragma unroll
    for (int k = 0; k < 3; ++k) {
      int p = atomicAdd(&bcnt[sel[k]], 1);
      sel_s[tid][k] = sel[k]; pos_s[tid][k] = p; g_s[tid][k] = sa[k] * inv;
    }
  }
  __syncthreads();
  if (tid < 16) bbase[tid] = atomicAdd(&counts[tid], bcnt[tid]);
  __syncthreads();
  if (tid < 4) {
    #pragma unroll
    for (int k = 0; k < 3; ++k) {
      int E = sel_s[tid][k];
      int p = bbase[E] + pos_s[tid][k];
      list[E * T_TOK + p] = blockIdx.x * 4 + tid;
      wgt [E * T_TOK + p] = g_s[tid][k];
    }
  }
}

// ---------------- GEMM1: 128x64 tiles, 512 thr / 8 waves -------------------
// Waves 0-3 compute accg, waves 4-7 compute accu (identical MFMA sequences
// per accumulator -> bit-identical to the 256-thr version); u exchanged via
// LDS at the epilogue. z==NE+1 slice: aux blocks convert sdn/edn + zero out.
__global__ __launch_bounds__(512, 4) void gemm1_fused(
    const unsigned short* __restrict__ X, const unsigned short* __restrict__ Wsh,
    const unsigned short* __restrict__ Wex, unsigned short* __restrict__ Hall,
    const int* __restrict__ counts, const int* __restrict__ list,
    const float* __restrict__ sdn, const float* __restrict__ edn,
    unsigned short* __restrict__ sdnb, unsigned short* __restrict__ ednb,
    float* __restrict__ out)
{
  const int tid = threadIdx.x;
  const int z = blockIdx.z;

  if (z == NE + 1) {
    // aux: zero out (262144 float4) + convert sdn/edn (557056 us8 groups)
    const int t = (blockIdx.y * 8 + blockIdx.x) * 512 + tid;  // 0..65535
    const float4 z4 = {0.f, 0.f, 0.f, 0.f};
    #pragma unroll
    for (int i = 0; i < 4; ++i) ((float4*)out)[t + i * 65536] = z4;
    for (int g = t; g < 557056; g += 65536) {
      const float* s; unsigned short* d; int l;
      if (g < 32768) { s = sdn; d = sdnb; l = g; }
      else           { s = edn; d = ednb; l = g - 32768; }
      const float* p = s + (size_t)l * 8;
      float4 v0 = *(const float4*)p;
      float4 v1 = *(const float4*)(p + 4);
      *(us8*)(d + (size_t)l * 8) = pack8(v0, v1);
    }
    return;
  }

  __shared__ __align__(1024) char smem[65536];
  // SA [2][128][64]us @0 (32KB) | SG [2][64][64]us @32768 | SU @49152
  // u_s float[128][65] overlays @0 after the final barrier.

  const int n0 = blockIdx.x * 64;           // H col block
  const int mt = blockIdx.y;
  int cnt, hb; const unsigned short* W;
  if (z == 0) { cnt = T_TOK; hb = 0; W = Wsh; }
  else {
    const int e = z - 1;
    cnt = counts[e];
    if (mt * 128 >= cnt) return;
    hb = T_TOK;
    for (int i = 0; i < e; ++i) hb += counts[i];
    W = Wex + (size_t)e * (2 * DFF * DM);
  }

  const int w = tid >> 6, lane = tid & 63;
  const bool is_u = w >= 4;
  const int wv = w & 3;

  // A staging: 8 waves x 16 rows (2 windows of 8)
  const int rA0 = w * 16 + (lane >> 3);
  const int cchA = (lane & 7) ^ (lane >> 3);
  const unsigned short* ga[2];
  #pragma unroll
  for (int q = 0; q < 2; ++q) {
    int ra = mt * 128 + rA0 + q * 8;
    int rc = ra < cnt ? ra : cnt - 1;
    int tokr = (z == 0) ? rc : list[(z - 1) * T_TOK + rc];
    ga[q] = X + (size_t)tokr * DM + cchA * 8;
  }
  // G/U staging: waves 0-3 stage G rows, waves 4-7 stage U rows (16 each)
  const int rB0 = wv * 16 + (lane >> 3);
  const unsigned short* gb[2];
  #pragma unroll
  for (int q = 0; q < 2; ++q) {
    int rb = n0 + rB0 + q * 8;
    gb[q] = W + (size_t)(is_u ? DFF + rb : rb) * DM + cchA * 8;
  }
  const int bb0 = is_u ? 49152 : 32768;
  unsigned short* lA[2][2]; unsigned short* lB[2][2];
  #pragma unroll
  for (int b = 0; b < 2; ++b)
    #pragma unroll
    for (int q = 0; q < 2; ++q) {
      lA[b][q] = (unsigned short*)(smem + b * 16384) + (w * 16 + q * 8) * 64;
      lB[b][q] = (unsigned short*)(smem + bb0 + b * 8192) + (wv * 16 + q * 8) * 64;
    }

  const int wm = (wv & 1) * 64;
  const int wn = (wv >> 1) * 32;
  const int lr = lane & 15, qd = lane >> 4;

  const f32x4 z4 = {0.f, 0.f, 0.f, 0.f};
  f32x4 acc[4][2];
  #pragma unroll
  for (int i = 0; i < 4; ++i)
    #pragma unroll
    for (int j = 0; j < 2; ++j) acc[i][j] = z4;

  // prologue: stage tile 0 into buf 0
  #pragma unroll
  for (int q = 0; q < 2; ++q) { dma16(ga[q], lA[0][q]); dma16(gb[q], lB[0][q]); }

  #pragma unroll
  for (int i = 0; i < DM / 64; ++i) {
    __syncthreads();                         // buf (i&1) ready (drains DMA)
    if (i + 1 < DM / 64) {
      const int k1 = (i + 1) * 64, nb = (i + 1) & 1;
      #pragma unroll
      for (int q = 0; q < 2; ++q) {
        dma16(ga[q] + k1, lA[nb][q]);
        dma16(gb[q] + k1, lB[nb][q]);
      }
    }
    const int boA = (i & 1) * 16384;
    const int boB = bb0 + (i & 1) * 8192;
    #pragma unroll
    for (int ks = 0; ks < 2; ++ks) {
      const int ch = ks * 4 + qd;
      bf16x8 a[4], bv[2];
      #pragma unroll
      for (int sm = 0; sm < 4; ++sm)
        a[sm] = *(const bf16x8*)(smem + boA + LDSOFF(wm + sm * 16 + lr, ch));
      #pragma unroll
      for (int sn = 0; sn < 2; ++sn)
        bv[sn] = *(const bf16x8*)(smem + boB + LDSOFF(wn + sn * 16 + lr, ch));
      #pragma unroll
      for (int sm = 0; sm < 4; ++sm)
        #pragma unroll
        for (int sn = 0; sn < 2; ++sn)
          acc[sm][sn] = MFMA(a[sm], bv[sn], acc[sm][sn]);
    }
  }

  // epilogue: u-waves publish accu via LDS (stride 65 breaks conflicts),
  // g-waves fuse silu(g)*u and store.
  __syncthreads();
  float* const us = (float*)smem;            // [128][65]
  if (is_u) {
    #pragma unroll
    for (int sm = 0; sm < 4; ++sm)
      #pragma unroll
      for (int sn = 0; sn < 2; ++sn) {
        const int col = wn + sn * 16 + lr;
        #pragma unroll
        for (int r = 0; r < 4; ++r)
          us[(wm + sm * 16 + qd * 4 + r) * 65 + col] = acc[sm][sn][r];
      }
  }
  __syncthreads();
  if (!is_u) {
    #pragma unroll
    for (int sm = 0; sm < 4; ++sm)
      #pragma unroll
      for (int sn = 0; sn < 2; ++sn) {
        const int col = n0 + wn + sn * 16 + lr;
        #pragma unroll
        for (int r = 0; r < 4; ++r) {
          const int ent = mt * 128 + wm + sm * 16 + qd * 4 + r;
          if (ent < cnt) {
            float g = acc[sm][sn][r];
            float u = us[(wm + sm * 16 + qd * 4 + r) * 65 + wn + sn * 16 + lr];
            float h = (g / (1.f + __expf(-g))) * u;   // silu(g)*u
            Hall[(size_t)(hb + ent) * DFF + col] = f2bf(h);
          }
        }
      }
  }
}

// ---------------- GEMM2: 128x64 tiles, 512 thr / 8 waves -------------------
// 8 waves = 2(M) x 4(N strips of 16); acc[4][1] per wave.
__global__ __launch_bounds__(512, 4) void gemm2_fused(
    const unsigned short* __restrict__ Hall, const unsigned short* __restrict__ Wsh,
    const unsigned short* __restrict__ Wex, float* __restrict__ out,
    const int* __restrict__ counts, const int* __restrict__ list,
    const float* __restrict__ wgt)
{
  __shared__ __align__(1024) char smem[49152];
  // SA [2][128][64]us @0 (32KB) | SB [2][64][64]us @32768 (16KB)

  const int n0 = blockIdx.x * 64;           // out col block
  const int mt = blockIdx.y, z = blockIdx.z;
  int cnt, hb; const unsigned short* W;
  if (z == 0) { cnt = T_TOK; hb = 0; W = Wsh; }
  else {
    const int e = z - 1;
    cnt = counts[e];
    if (mt * 128 >= cnt) return;
    hb = T_TOK;
    for (int i = 0; i < e; ++i) hb += counts[i];
    W = Wex + (size_t)e * (DM * DFF);
  }

  const int tid = threadIdx.x, w = tid >> 6, lane = tid & 63;
  // A staging: 8 waves x 16 rows (2 windows)
  const int rA0 = w * 16 + (lane >> 3);
  const int cchA = (lane & 7) ^ (lane >> 3);
  const unsigned short* ga[2];
  #pragma unroll
  for (int q = 0; q < 2; ++q) {
    int ra = mt * 128 + rA0 + q * 8;
    int rc = ra < cnt ? ra : cnt - 1;
    ga[q] = Hall + (size_t)(hb + rc) * DFF + cchA * 8;
  }
  // B staging: 8 waves x 8 rows (1 window)
  const int rB0 = w * 8 + (lane >> 3);
  const unsigned short* gb = W + (size_t)(n0 + rB0) * DFF + cchA * 8;

  unsigned short* lA[2][2]; unsigned short* lB[2];
  #pragma unroll
  for (int b = 0; b < 2; ++b) {
    #pragma unroll
    for (int q = 0; q < 2; ++q)
      lA[b][q] = (unsigned short*)(smem + b * 16384) + (w * 16 + q * 8) * 64;
    lB[b] = (unsigned short*)(smem + 32768 + b * 8192) + (w * 8) * 64;
  }

  const int wm = (w & 1) * 64;
  const int wn = (w >> 1) * 16;              // 4 N-strips of 16
  const int lr = lane & 15, qd = lane >> 4;

  const f32x4 z4 = {0.f, 0.f, 0.f, 0.f};
  f32x4 acc[4];
  #pragma unroll
  for (int i = 0; i < 4; ++i) acc[i] = z4;

  // prologue
  #pragma unroll
  for (int q = 0; q < 2; ++q) dma16(ga[q], lA[0][q]);
  dma16(gb, lB[0]);

  #pragma unroll
  for (int i = 0; i < DFF / 64; ++i) {
    __syncthreads();
    if (i + 1 < DFF / 64) {
      const int k1 = (i + 1) * 64, nb = (i + 1) & 1;
      #pragma unroll
      for (int q = 0; q < 2; ++q) dma16(ga[q] + k1, lA[nb][q]);
      dma16(gb + k1, lB[nb]);
    }
    const int boA = (i & 1) * 16384;
    const int boB = 32768 + (i & 1) * 8192;
    #pragma unroll
    for (int ks = 0; ks < 2; ++ks) {
      const int ch = ks * 4 + qd;
      bf16x8 a[4];
      #pragma unroll
      for (int sm = 0; sm < 4; ++sm)
        a[sm] = *(const bf16x8*)(smem + boA + LDSOFF(wm + sm * 16 + lr, ch));
      bf16x8 bv = *(const bf16x8*)(smem + boB + LDSOFF(wn + lr, ch));
      #pragma unroll
      for (int sm = 0; sm < 4; ++sm)
        acc[sm] = MFMA(a[sm], bv, acc[sm]);
    }
  }

  #pragma unroll
  for (int sm = 0; sm < 4; ++sm) {
    const int col = n0 + wn + lr;
    #pragma unroll
    for (int r = 0; r < 4; ++r) {
      const int ent = mt * 128 + wm + sm * 16 + qd * 4 + r;
      if (ent < cnt) {
        float v = acc[sm][r];
        if (z == 0) {
          atomicAdd(out + (size_t)ent * DM + col, v);
        } else {
          const int   tok = list[(z - 1) * T_TOK + ent];
          const float g   = wgt [(z - 1) * T_TOK + ent];
          atomicAdd(out + (size_t)tok * DM + col, g * v);
        }
      }
    }
  }
}

// ---------------------------------------------------------------------------
extern "C" void kernel_launch(void* const* d_in, const int* in_sizes, int n_in,
                              void* d_out, int out_size, void* d_ws, size_t ws_size,
                              hipStream_t stream) {
  const float* x    = (const float*)d_in[0];
  const float* gw   = (const float*)d_in[1];
  const float* bias = (const float*)d_in[2];
  const float* sgu  = (const float*)d_in[3];
  const float* sdn  = (const float*)d_in[4];
  const float* egu  = (const float*)d_in[5];
  const float* edn  = (const float*)d_in[6];
  float* out = (float*)d_out;

  // workspace layout (bytes)
  char* ws = (char*)d_ws;
  int*            counts = (int*)(ws + 0);        // 16 ints
  int*            list   = (int*)(ws + 64);       // 16*2048 ints
  float*          wgt    = (float*)(ws + 131136); // 16*2048 floats
  unsigned short* Hall   = (unsigned short*)(ws + 262208); // 8192*512 bf16
  unsigned short* xb     = (unsigned short*)(ws + 8650816);
  unsigned short* sgub   = (unsigned short*)(ws + 10747968);
  unsigned short* sdnb   = (unsigned short*)(ws + 11796544);
  unsigned short* egub   = (unsigned short*)(ws + 12320832);
  unsigned short* ednb   = (unsigned short*)(ws + 29098048);
  const size_t need = 37486656;
  if (ws_size < need) return;

  hipMemsetAsync(counts, 0, 64, stream);
  prep_kernel<<<512 + 4864, 256, 0, stream>>>(
      x, gw, bias, counts, list, wgt, sgu, egu, xb, sgub, egub);
  gemm1_fused<<<dim3(8, 16, NE + 2), 512, 0, stream>>>(
      xb, sgub, egub, Hall, counts, list, sdn, edn, sdnb, ednb, out);
  gemm2_fused<<<dim3(8, 16, NE + 1), 512, 0, stream>>>(
      Hall, sdnb, ednb, out, counts, list, wgt);
}

// Round 6
// 162.724 us; speedup vs baseline: 3.6607x; 1.0061x over previous
//
#include <hip/hip_runtime.h>

#define T_TOK 2048
#define DM    512
#define DFF   512
#define NE    16

typedef __attribute__((ext_vector_type(8))) short bf16x8;
typedef __attribute__((ext_vector_type(4))) float f32x4;
typedef __attribute__((ext_vector_type(8))) unsigned short us8;

__device__ __forceinline__ unsigned short f2bf(float f) {
  unsigned int u = __float_as_uint(f);
  u += 0x7fffu + ((u >> 16) & 1u);   // round-to-nearest-even
  return (unsigned short)(u >> 16);
}

__device__ __forceinline__ us8 pack8(float4 v0, float4 v1) {
  us8 o;
  o[0]=f2bf(v0.x); o[1]=f2bf(v0.y); o[2]=f2bf(v0.z); o[3]=f2bf(v0.w);
  o[4]=f2bf(v1.x); o[5]=f2bf(v1.y); o[6]=f2bf(v1.z); o[7]=f2bf(v1.w);
  return o;
}

// async global->LDS DMA, 16 B per lane; lds base must be wave-uniform
__device__ __forceinline__ void dma16(const unsigned short* g, unsigned short* l) {
  __builtin_amdgcn_global_load_lds(
      (const __attribute__((address_space(1))) unsigned int*)g,
      (__attribute__((address_space(3))) unsigned int*)l, 16, 0, 0);
}

// XOR-swizzled LDS tile rows of 64 bf16 (128 B/row), chunk c of row r
// stored at slot c ^ (r & 7). DMA windows (1024 B) stay contiguous; readers
// get 2-way bank aliasing (free, m136).
#define LDSOFF(row, chunk) ((((row) << 7) + ((((chunk) ^ ((row) & 7))) << 4)))

#define MFMA(a,b,c) __builtin_amdgcn_mfma_f32_16x16x32_bf16((a),(b),(c),0,0,0)

// ---------------- prep: blocks 0..511 router, 512+ convert x|sgu|egu -------
__global__ __launch_bounds__(256) void prep_kernel(
    const float* __restrict__ x, const float* __restrict__ gw,
    const float* __restrict__ bias, int* __restrict__ counts,
    int* __restrict__ list, float* __restrict__ wgt,
    const float* __restrict__ sgu, const float* __restrict__ egu,
    unsigned short* __restrict__ xb, unsigned short* __restrict__ sgub,
    unsigned short* __restrict__ egub)
{
  const int tid = threadIdx.x;
  if (blockIdx.x >= 512) {
    // convert groups of 8 fp32->bf16: x 131072 | sgu 65536 | egu 1048576
    const int g = (blockIdx.x - 512) * 256 + tid;   // 0..1245183
    const float* s; unsigned short* d; int l;
    if      (g <  131072) { s = x;   d = xb;   l = g;          }
    else if (g <  196608) { s = sgu; d = sgub; l = g - 131072; }
    else                  { s = egu; d = egub; l = g - 196608; }
    const float* p = s + (size_t)l * 8;
    float4 v0 = *(const float4*)p;
    float4 v1 = *(const float4*)(p + 4);
    *(us8*)(d + (size_t)l * 8) = pack8(v0, v1);
    return;
  }

  // ---- router: one token per wave ----
  __shared__ float lg[4][16];
  __shared__ int bcnt[16], bbase[16];
  __shared__ int sel_s[4][3], pos_s[4][3];
  __shared__ float g_s[4][3];

  const int w = tid >> 6, lane = tid & 63;
  if (tid < 16) bcnt[tid] = 0;
  const int tok = blockIdx.x * 4 + w;
  const int e = lane & 15, part = lane >> 4;

  const float* xr = x + (size_t)tok * DM + part * 128;
  const float* wr = gw + (size_t)e * DM + part * 128;
  float acc = 0.f;
  #pragma unroll 8
  for (int i = 0; i < 128; i += 4) {
    float4 xv = *(const float4*)(xr + i);
    float4 wv = *(const float4*)(wr + i);
    acc += xv.x*wv.x + xv.y*wv.y + xv.z*wv.z + xv.w*wv.w;
  }
  acc += __shfl_xor(acc, 16);
  acc += __shfl_xor(acc, 32);
  if (lane < 16) lg[w][lane] = 1.f / (1.f + __expf(-acc));  // affinity
  __syncthreads();

  if (tid < 4) {
    float aff[16], sc[16];
    #pragma unroll
    for (int i = 0; i < 16; ++i) { aff[i] = lg[tid][i]; sc[i] = aff[i] + bias[i]; }
    int sel[3]; float sa[3]; float sum = 0.f;
    #pragma unroll
    for (int k = 0; k < 3; ++k) {
      float best = -1e30f; int bi = 0;
      for (int i = 0; i < 16; ++i) {
        bool used = false;
        for (int j = 0; j < k; ++j) used |= (sel[j] == i);
        if (!used && sc[i] > best) { best = sc[i]; bi = i; }
      }
      sel[k] = bi; sa[k] = aff[bi]; sum += aff[bi];
    }
    float inv = 1.f / (sum + 1e-9f);
    #pragma unroll
    for (int k = 0; k < 3; ++k) {
      int p = atomicAdd(&bcnt[sel[k]], 1);
      sel_s[tid][k] = sel[k]; pos_s[tid][k] = p; g_s[tid][k] = sa[k] * inv;
    }
  }
  __syncthreads();
  if (tid < 16) bbase[tid] = atomicAdd(&counts[tid], bcnt[tid]);
  __syncthreads();
  if (tid < 4) {
    #pragma unroll
    for (int k = 0; k < 3; ++k) {
      int E = sel_s[tid][k];
      int p = bbase[E] + pos_s[tid][k];
      list[E * T_TOK + p] = blockIdx.x * 4 + tid;
      wgt [E * T_TOK + p] = g_s[tid][k];
    }
  }
}

// ---------------- GEMM1: 64x64 tiles, 512 thr / 8 waves, 48KB LDS ---------
// 3 blocks/CU. Waves 0-3 compute G quadrants, waves 4-7 compute U quadrants
// (identical MFMA sequences per accumulator -> bit-identical numerics);
// u exchanged via LDS overlay at the epilogue.
// z==NE+1 slice: aux blocks convert sdn/edn + zero out.
__global__ __launch_bounds__(512, 6) void gemm1_fused(
    const unsigned short* __restrict__ X, const unsigned short* __restrict__ Wsh,
    const unsigned short* __restrict__ Wex, unsigned short* __restrict__ Hall,
    const int* __restrict__ counts, const int* __restrict__ list,
    const float* __restrict__ sdn, const float* __restrict__ edn,
    unsigned short* __restrict__ sdnb, unsigned short* __restrict__ ednb,
    float* __restrict__ out)
{
  __shared__ __align__(1024) char smem[49152];
  // SA [2][64][64]us @0 (16KB) | SG @16384 (16KB) | SU @32768 (16KB)
  // u_s float[64][65] overlays @0 after the final barrier.
  const int tid = threadIdx.x;
  const int z = blockIdx.z;

  if (z == NE + 1) {
    // aux (256 blocks): zero out (262144 float4) + convert sdn/edn
    const int t = (blockIdx.y * 8 + blockIdx.x) * 512 + tid;  // 0..131071
    const float4 z4 = {0.f, 0.f, 0.f, 0.f};
    ((float4*)out)[t] = z4;
    ((float4*)out)[t + 131072] = z4;
    for (int g = t; g < 557056; g += 131072) {
      const float* s; unsigned short* d; int l;
      if (g < 32768) { s = sdn; d = sdnb; l = g; }
      else           { s = edn; d = ednb; l = g - 32768; }
      const float* p = s + (size_t)l * 8;
      float4 v0 = *(const float4*)p;
      float4 v1 = *(const float4*)(p + 4);
      *(us8*)(d + (size_t)l * 8) = pack8(v0, v1);
    }
    return;
  }

  const int n0 = blockIdx.x * 64;           // H col block
  const int mt = blockIdx.y;
  int cnt, hb; const unsigned short* W;
  if (z == 0) { cnt = T_TOK; hb = 0; W = Wsh; }
  else {
    const int e = z - 1;
    cnt = counts[e];
    if (mt * 64 >= cnt) return;
    hb = T_TOK;
    for (int i = 0; i < e; ++i) hb += counts[i];
    W = Wex + (size_t)e * (2 * DFF * DM);
  }

  const int w = tid >> 6, lane = tid & 63;
  const bool is_u = w >= 4;
  const int wv = w & 3;

  // A staging: 8 waves x 8 rows (1 window each)
  const int rA0 = w * 8 + (lane >> 3);
  const int cchA = (lane & 7) ^ (lane >> 3);   // row&7 == lane>>3 everywhere
  int raA = mt * 64 + rA0;
  int rcA = raA < cnt ? raA : cnt - 1;
  int tokr = (z == 0) ? rcA : list[(z - 1) * T_TOK + rcA];
  const unsigned short* ga = X + (size_t)tokr * DM + cchA * 8;

  // G/U staging: waves 0-3 stage G (16 rows = 2 windows), waves 4-7 stage U
  const int rB0 = wv * 16 + (lane >> 3);
  const unsigned short* gb[2];
  #pragma unroll
  for (int q = 0; q < 2; ++q) {
    int rb = n0 + rB0 + q * 8;
    gb[q] = W + (size_t)(is_u ? DFF + rb : rb) * DM + cchA * 8;
  }
  const int bb0 = is_u ? 32768 : 16384;
  unsigned short* lA[2]; unsigned short* lB[2][2];
  #pragma unroll
  for (int b = 0; b < 2; ++b) {
    lA[b] = (unsigned short*)(smem + b * 8192) + (w * 8) * 64;
    #pragma unroll
    for (int q = 0; q < 2; ++q)
      lB[b][q] = (unsigned short*)(smem + bb0 + b * 8192) + (wv * 16 + q * 8) * 64;
  }

  const int wm = (wv & 1) * 32;
  const int wn = (wv >> 1) * 32;
  const int lr = lane & 15, qd = lane >> 4;

  const f32x4 z4 = {0.f, 0.f, 0.f, 0.f};
  f32x4 acc[2][2];
  #pragma unroll
  for (int i = 0; i < 2; ++i)
    #pragma unroll
    for (int j = 0; j < 2; ++j) acc[i][j] = z4;

  // prologue: stage tile 0 into buf 0
  dma16(ga, lA[0]);
  #pragma unroll
  for (int q = 0; q < 2; ++q) dma16(gb[q], lB[0][q]);

  #pragma unroll
  for (int i = 0; i < DM / 64; ++i) {
    __syncthreads();                         // buf (i&1) ready (drains DMA)
    if (i + 1 < DM / 64) {
      const int k1 = (i + 1) * 64, nb = (i + 1) & 1;
      dma16(ga + k1, lA[nb]);
      #pragma unroll
      for (int q = 0; q < 2; ++q) dma16(gb[q] + k1, lB[nb][q]);
    }
    const int boA = (i & 1) * 8192;
    const int boB = bb0 + (i & 1) * 8192;
    #pragma unroll
    for (int ks = 0; ks < 2; ++ks) {
      const int ch = ks * 4 + qd;
      bf16x8 a[2], bv[2];
      #pragma unroll
      for (int sm = 0; sm < 2; ++sm)
        a[sm] = *(const bf16x8*)(smem + boA + LDSOFF(wm + sm * 16 + lr, ch));
      #pragma unroll
      for (int sn = 0; sn < 2; ++sn)
        bv[sn] = *(const bf16x8*)(smem + boB + LDSOFF(wn + sn * 16 + lr, ch));
      #pragma unroll
      for (int sm = 0; sm < 2; ++sm)
        #pragma unroll
        for (int sn = 0; sn < 2; ++sn)
          acc[sm][sn] = MFMA(a[sm], bv[sn], acc[sm][sn]);
    }
  }

  // epilogue: u-waves publish accu via LDS (stride 65 breaks conflicts),
  // g-waves fuse silu(g)*u and store.
  __syncthreads();
  float* const us = (float*)smem;            // [64][65]
  if (is_u) {
    #pragma unroll
    for (int sm = 0; sm < 2; ++sm)
      #pragma unroll
      for (int sn = 0; sn < 2; ++sn) {
        const int col = wn + sn * 16 + lr;
        #pragma unroll
        for (int r = 0; r < 4; ++r)
          us[(wm + sm * 16 + qd * 4 + r) * 65 + col] = acc[sm][sn][r];
      }
  }
  __syncthreads();
  if (!is_u) {
    #pragma unroll
    for (int sm = 0; sm < 2; ++sm)
      #pragma unroll
      for (int sn = 0; sn < 2; ++sn) {
        const int col = n0 + wn + sn * 16 + lr;
        #pragma unroll
        for (int r = 0; r < 4; ++r) {
          const int ent = mt * 64 + wm + sm * 16 + qd * 4 + r;
          if (ent < cnt) {
            float g = acc[sm][sn][r];
            float u = us[(wm + sm * 16 + qd * 4 + r) * 65 + wn + sn * 16 + lr];
            float h = (g / (1.f + __expf(-g))) * u;   // silu(g)*u
            Hall[(size_t)(hb + ent) * DFF + col] = f2bf(h);
          }
        }
      }
  }
}

// ---------------- GEMM2: 64x64 tiles, 512 thr / 8 waves, 32KB LDS ---------
// 4 blocks/CU (100% occupancy). 8 waves = 2(M of 32) x 4(N strips of 16).
__global__ __launch_bounds__(512, 8) void gemm2_fused(
    const unsigned short* __restrict__ Hall, const unsigned short* __restrict__ Wsh,
    const unsigned short* __restrict__ Wex, float* __restrict__ out,
    const int* __restrict__ counts, const int* __restrict__ list,
    const float* __restrict__ wgt)
{
  __shared__ __align__(1024) char smem[32768];
  // SA [2][64][64]us @0 (16KB) | SB [2][64][64]us @16384 (16KB)

  const int n0 = blockIdx.x * 64;           // out col block
  const int mt = blockIdx.y, z = blockIdx.z;
  int cnt, hb; const unsigned short* W;
  if (z == 0) { cnt = T_TOK; hb = 0; W = Wsh; }
  else {
    const int e = z - 1;
    cnt = counts[e];
    if (mt * 64 >= cnt) return;
    hb = T_TOK;
    for (int i = 0; i < e; ++i) hb += counts[i];
    W = Wex + (size_t)e * (DM * DFF);
  }

  const int tid = threadIdx.x, w = tid >> 6, lane = tid & 63;
  // A staging: 8 waves x 8 rows (1 window)
  const int rA0 = w * 8 + (lane >> 3);
  const int cchA = (lane & 7) ^ (lane >> 3);
  int ra = mt * 64 + rA0;
  int rc = ra < cnt ? ra : cnt - 1;
  const unsigned short* ga = Hall + (size_t)(hb + rc) * DFF + cchA * 8;
  // B staging: 8 waves x 8 rows (1 window)
  const unsigned short* gb = W + (size_t)(n0 + rA0) * DFF + cchA * 8;

  unsigned short* lA[2]; unsigned short* lB[2];
  #pragma unroll
  for (int b = 0; b < 2; ++b) {
    lA[b] = (unsigned short*)(smem + b * 8192) + (w * 8) * 64;
    lB[b] = (unsigned short*)(smem + 16384 + b * 8192) + (w * 8) * 64;
  }

  const int wm = (w & 1) * 32;
  const int wn = (w >> 1) * 16;              // 4 N-strips of 16
  const int lr = lane & 15, qd = lane >> 4;

  const f32x4 z4 = {0.f, 0.f, 0.f, 0.f};
  f32x4 acc[2];
  #pragma unroll
  for (int i = 0; i < 2; ++i) acc[i] = z4;

  // prologue
  dma16(ga, lA[0]);
  dma16(gb, lB[0]);

  #pragma unroll
  for (int i = 0; i < DFF / 64; ++i) {
    __syncthreads();
    if (i + 1 < DFF / 64) {
      const int k1 = (i + 1) * 64, nb = (i + 1) & 1;
      dma16(ga + k1, lA[nb]);
      dma16(gb + k1, lB[nb]);
    }
    const int boA = (i & 1) * 8192;
    const int boB = 16384 + (i & 1) * 8192;
    #pragma unroll
    for (int ks = 0; ks < 2; ++ks) {
      const int ch = ks * 4 + qd;
      bf16x8 a[2];
      #pragma unroll
      for (int sm = 0; sm < 2; ++sm)
        a[sm] = *(const bf16x8*)(smem + boA + LDSOFF(wm + sm * 16 + lr, ch));
      bf16x8 bv = *(const bf16x8*)(smem + boB + LDSOFF(wn + lr, ch));
      #pragma unroll
      for (int sm = 0; sm < 2; ++sm)
        acc[sm] = MFMA(a[sm], bv, acc[sm]);
    }
  }

  #pragma unroll
  for (int sm = 0; sm < 2; ++sm) {
    const int col = n0 + wn + lr;
    #pragma unroll
    for (int r = 0; r < 4; ++r) {
      const int ent = mt * 64 + wm + sm * 16 + qd * 4 + r;
      if (ent < cnt) {
        float v = acc[sm][r];
        if (z == 0) {
          atomicAdd(out + (size_t)ent * DM + col, v);
        } else {
          const int   tok = list[(z - 1) * T_TOK + ent];
          const float g   = wgt [(z - 1) * T_TOK + ent];
          atomicAdd(out + (size_t)tok * DM + col, g * v);
        }
      }
    }
  }
}

// ---------------------------------------------------------------------------
extern "C" void kernel_launch(void* const* d_in, const int* in_sizes, int n_in,
                              void* d_out, int out_size, void* d_ws, size_t ws_size,
                              hipStream_t stream) {
  const float* x    = (const float*)d_in[0];
  const float* gw   = (const float*)d_in[1];
  const float* bias = (const float*)d_in[2];
  const float* sgu  = (const float*)d_in[3];
  const float* sdn  = (const float*)d_in[4];
  const float* egu  = (const float*)d_in[5];
  const float* edn  = (const float*)d_in[6];
  float* out = (float*)d_out;

  // workspace layout (bytes)
  char* ws = (char*)d_ws;
  int*            counts = (int*)(ws + 0);        // 16 ints
  int*            list   = (int*)(ws + 64);       // 16*2048 ints
  float*          wgt    = (float*)(ws + 131136); // 16*2048 floats
  unsigned short* Hall   = (unsigned short*)(ws + 262208); // 8192*512 bf16
  unsigned short* xb     = (unsigned short*)(ws + 8650816);
  unsigned short* sgub   = (unsigned short*)(ws + 10747968);
  unsigned short* sdnb   = (unsigned short*)(ws + 11796544);
  unsigned short* egub   = (unsigned short*)(ws + 12320832);
  unsigned short* ednb   = (unsigned short*)(ws + 29098048);
  const size_t need = 37486656;
  if (ws_size < need) return;

  hipMemsetAsync(counts, 0, 64, stream);
  prep_kernel<<<512 + 4864, 256, 0, stream>>>(
      x, gw, bias, counts, list, wgt, sgu, egu, xb, sgub, egub);
  gemm1_fused<<<dim3(8, 32, NE + 2), 512, 0, stream>>>(
      xb, sgub, egub, Hall, counts, list, sdn, edn, sdnb, ednb, out);
  gemm2_fused<<<dim3(8, 32, NE + 1), 512, 0, stream>>>(
      Hall, sdnb, ednb, out, counts, list, wgt);
}